// Round 7
// baseline (287.516 us; speedup 1.0000x reference)
//
#include <hip/hip_runtime.h>
#include <hip/hip_bf16.h>

#define BDIM 2048
#define WDIM 128
#define FDIM 8
#define HDIM 256

typedef __bf16 b8 __attribute__((ext_vector_type(8)));
typedef __bf16 b4 __attribute__((ext_vector_type(4)));
typedef float f32x4 __attribute__((ext_vector_type(4)));

// workspace layout (bytes), all 16B aligned
#define OFF_RZ  0                 // 256 frags * 1KB (r,z Whh A-frags)
#define OFF_N   262144            // 128 frags * 1KB (n Whh A-frags -> LDS)
#define OFF_WIH 393216            // 48 frags * 1KB  (Wih A-frags + bias in k=8, pinned)
#define OFF_WP  442368            // 256 frags * 1KB (Wp B-frags)
#define OFF_XB  704512            // 2048*128*8 bf16 = 4194304
// total 4,898,816 B

// dynamic LDS: [0,16K) h dbuf (2x8KB) ; [16K,144K) n-gate frags (16 waves x 8 x 1KB)
// tail overlay: [0,16K) lastb[16][512] bf16 ; [16K,32K) ybuf[16][256] f32
#define SMEM_BYTES 147456

#define MFMA(a,b,c) __builtin_amdgcn_mfma_f32_16x16x32_bf16((a),(b),(c),0,0,0)

static __device__ __forceinline__ float sig_(float v) {
    return __builtin_amdgcn_rcpf(1.0f + __expf(-v));
}
static __device__ __forceinline__ float tanh_(float v) {
    // tanh(v) = 1 - 2/(exp(2v)+1); saturates correctly at +-inf
    return fmaf(-2.0f, __builtin_amdgcn_rcpf(1.0f + __expf(2.0f * v)), 1.0f);
}

// ---------------- pack: weights/x -> bf16 MFMA fragments ----------------
// A-frag (16x16x32): lane l holds A[i = l&15][k = kt*32 + (l>>4)*8 + e]
// B-frag:            lane l holds B[k = kt*32 + (l>>4)*8 + e][j = l&15]
__global__ void pack_kernel(const float* __restrict__ x,
                            const float* __restrict__ Wih_f,
                            const float* __restrict__ Whh_f,
                            const float* __restrict__ bih_f,
                            const float* __restrict__ bhh_f,
                            const float* __restrict__ Wp,
                            unsigned char* __restrict__ ws)
{
    int idx = blockIdx.x * 256 + threadIdx.x;
    if (idx < 16384) {                       // r,z Whh A-frags: f = (p*4+2g+nt)*8+kt, p=mtile>>1
        int l = idx & 63, f = idx >> 6;
        int kt = f & 7, nt = (f >> 3) & 1, g = (f >> 4) & 1, p = f >> 5;
        int gch = g * HDIM + 32 * p + 16 * nt + (l & 15);
        int kb = kt * 32 + (l >> 4) * 8;
        b8 v;
        #pragma unroll
        for (int e = 0; e < 8; ++e) v[e] = (__bf16)Whh_f[gch * HDIM + kb + e];
        ((b8*)(ws + OFF_RZ))[idx] = v;
    } else if (idx < 24576) {                // n Whh A-frags: f = mtile*8+kt
        int j = idx - 16384;
        int l = j & 63, f = j >> 6;
        int kt = f & 7, m = f >> 3;
        int gch = 2 * HDIM + 16 * m + (l & 15);
        int kb = kt * 32 + (l >> 4) * 8;
        b8 v;
        #pragma unroll
        for (int e = 0; e < 8; ++e) v[e] = (__bf16)Whh_f[gch * HDIM + kb + e];
        ((b8*)(ws + OFF_N))[j] = v;
    } else if (idx < 27648) {                // Wih A-frags: f = (p*3+g)*2+nt (K=8 real, bias k=8)
        int j = idx - 24576;
        int l = j & 63, f = j >> 6;
        int nt = f & 1, q = f >> 1, g = q % 3, p = q / 3;
        int gch = g * HDIM + 32 * p + 16 * nt + (l & 15);
        int lq = l >> 4;
        b8 v;
        #pragma unroll
        for (int e = 0; e < 8; ++e) v[e] = (__bf16)0.0f;
        if (lq == 0) {
            #pragma unroll
            for (int e = 0; e < 8; ++e) v[e] = (__bf16)Wih_f[gch * FDIM + e];
        } else if (lq == 1) {
            float b = (g == 2) ? bih_f[gch] : (bih_f[gch] + bhh_f[gch]);
            v[0] = (__bf16)b;                // pairs with 1.0 in x B-frag k=8
        }
        ((b8*)(ws + OFF_WIH))[j] = v;
    } else if (idx < 44032) {                // Wp B-frags
        int j = idx - 27648;
        int l = j & 63, nk = j >> 6;
        int NT = nk >> 4, kt = nk & 15;
        int col = NT * 16 + (l & 15);
        int kb = kt * 32 + (l >> 4) * 8;
        b8 v;
        #pragma unroll
        for (int e = 0; e < 8; ++e) v[e] = (__bf16)Wp[col * (2 * HDIM) + kb + e];
        ((b8*)(ws + OFF_WP))[j] = v;
    } else if (idx < 44032 + 262144) {       // x -> bf16 rows [row][t][8]
        int j = idx - 44032;
        const float* src = x + j * 8;
        b8 v;
        #pragma unroll
        for (int e = 0; e < 8; ++e) v[e] = (__bf16)src[e];
        ((b8*)(ws + OFF_XB))[j] = v;
    }
}

// ---------------- fused GRU: 128 blocks x 1024 threads (16 waves), 16 rows/block ----------------
// Wave w (0..15) owns gate channels [16w, 16w+16) of r, z, n. NO tile waste.
// r,z Whh (16 frags) + Wih (3 frags) pinned in regs; n Whh in LDS.
// 4 waves/SIMD (128-reg cap). D[i=gatech][j=batchrow]: lane: row = l&15, ch = 16w+4*(l>>4)+j.
__global__ __launch_bounds__(1024, 4)
void gru_main_kernel(const float* __restrict__ x,
                     const float* __restrict__ bhh_f,
                     const float* __restrict__ Wih_b, const float* __restrict__ bih_b,
                     const float* __restrict__ bhh_b,
                     const float* __restrict__ bp,
                     const float* __restrict__ gamma, const float* __restrict__ beta,
                     const unsigned char* __restrict__ ws,
                     float* __restrict__ out)
{
    extern __shared__ __align__(16) unsigned char smem[];
    __bf16* hbB = (__bf16*)smem;                            // [0,16K) h dbuf 2x8KB
    b8* nlds = (b8*)(smem + 16384);                         // [16K,144K) n frags
    __bf16 (*lastb)[2 * HDIM] = (__bf16(*)[2 * HDIM])smem;  // tail overlay [0,16K)
    float  (*ybuf)[HDIM]      = (float(*)[HDIM])(smem + 16384); // [16K,32K)

    const int tid = threadIdx.x, lane = tid & 63, w = tid >> 6;   // w 0..15
    const int l15 = lane & 15, lq = lane >> 4;
    const int blockRow = blockIdx.x * 16;

    const b8* wsRZ = (const b8*)(ws + OFF_RZ);
    const b8* wsN  = (const b8*)(ws + OFF_N);
    const b8* wsWI = (const b8*)(ws + OFF_WIH);
    const b8* wsWP = (const b8*)(ws + OFF_WP);
    const b8* xB   = (const b8*)(ws + OFF_XB);

    const f32x4 zero4 = {0.f, 0.f, 0.f, 0.f};

    // zero h dbuf (16KB): 1024 threads x 16B
    *(f32x4*)(smem + tid * 16) = zero4;

    // stage this wave's 8 n-gate frags into LDS (one-time)
    {
        const b8* src = wsN + (w * 8) * 64 + lane;
        b8* dst = nlds + (w * 8) * 64 + lane;
        #pragma unroll
        for (int i = 0; i < 8; ++i) dst[i * 64] = src[i * 64];
    }

    // pinned A-frags: r,z Whh (16) + Wih (3) = 76 regs
    b8 whr[8], whz[8], wfr, wfz, wfn;
    {
        const int p = w >> 1, nt = w & 1;
        #pragma unroll
        for (int kt = 0; kt < 8; ++kt) {
            whr[kt] = wsRZ[((p * 4 + 0 + nt) * 8 + kt) * 64 + lane];
            whz[kt] = wsRZ[((p * 4 + 2 + nt) * 8 + kt) * 64 + lane];
        }
        const int pw = p * 3;
        wfr = wsWI[((pw + 0) * 2 + nt) * 64 + lane];
        wfz = wsWI[((pw + 1) * 2 + nt) * 64 + lane];
        wfn = wsWI[((pw + 2) * 2 + nt) * 64 + lane];
    }
    #pragma unroll
    for (int kt = 0; kt < 8; ++kt) {
        asm volatile("" : "+v"(whr[kt]));
        asm volatile("" : "+v"(whz[kt]));
    }
    asm volatile("" : "+v"(wfr));
    asm volatile("" : "+v"(wfz));
    asm volatile("" : "+v"(wfn));

    // bhh_n accumulator-init (C reg j <-> gatech 16w + 4lq + j)
    const float4 bnv = *(const float4*)&bhh_f[2 * HDIM + 16 * w + 4 * lq];

    // constant part of x B-frag: k=8 -> 1.0 (bias multiplier)
    b8 xc;
    #pragma unroll
    for (int e = 0; e < 8; ++e) xc[e] = (__bf16)0.0f;
    if (lq == 1) xc[0] = (__bf16)1.0f;

    // h master state in regs: (row=l15, ch=16w+4lq+j)
    f32x4 h0 = zero4;

    const int kswz = (8 * lq) ^ ((l15 & 7) << 3);     // B-read swizzle base
    const int c0 = 16 * w + 4 * lq;                   // this lane's channel base
    const int wswz = (l15 & 7) << 3;                  // write swizzle
    const b8* nW = nlds + (w * 8) * 64 + lane;
    const b8* xRow = xB + (blockRow + l15) * WDIM;

    __syncthreads();

    int cur = 0;
    for (int t = 0; t < WDIM; ++t) {
        // issue x load early; kt loop covers the latency
        b8 xf = xc;
        if (lane < 16) xf = xRow[t];

        f32x4 aR = zero4, aZ = zero4;
        f32x4 aNH;
        aNH[0] = bnv.x; aNH[1] = bnv.y; aNH[2] = bnv.z; aNH[3] = bnv.w;

        const __bf16* hc = hbB + cur * 4096 + l15 * 256;
        #pragma unroll
        for (int kt = 0; kt < 8; ++kt) {
            b8 hfrag = *(const b8*)(hc + ((kt << 5) ^ kswz));
            b8 nf = nW[kt * 64];
            aR  = MFMA(whr[kt], hfrag, aR);
            aZ  = MFMA(whz[kt], hfrag, aZ);
            aNH = MFMA(nf, hfrag, aNH);
        }
        // x-part (+ r,z biases via k=8 slot)
        aR = MFMA(wfr, xf, aR);
        aZ = MFMA(wfz, xf, aZ);
        f32x4 aNX = MFMA(wfn, xf, zero4);

        // gate fusion (h master in regs); all 16 rows real
        __bf16* hn = hbB + (cur ^ 1) * 4096;
        b4 v0;
        #pragma unroll
        for (int j = 0; j < 4; ++j) {
            float r = sig_(aR[j]);
            float z = sig_(aZ[j]);
            float n = tanh_(fmaf(r, aNH[j], aNX[j]));
            float hv = n + z * (h0[j] - n);
            h0[j] = hv; v0[j] = (__bf16)hv;
        }
        *(b4*)(hn + l15 * 256 + (c0 ^ wswz)) = v0;

        cur ^= 1;
        __syncthreads();
    }

    // ---- write forward h into lastb cols [0,256) ----
    {
        b4 v0;
        #pragma unroll
        for (int j = 0; j < 4; ++j) v0[j] = (__bf16)h0[j];
        *(b4*)(&lastb[l15][0] + (c0 ^ wswz)) = v0;
    }

    // ---- backward cell (h0=0, one step on x[:,127,:]) -> lastb cols [256,512) ----
    {
        const int trow = tid >> 6;           // 0..15
        const int cb = tid & 63;
        const float4* xr = (const float4*)(x + (blockRow + trow) * WDIM * FDIM + 127 * FDIM);
        float4 xv0 = xr[0], xv1 = xr[1];
        const float4* wb = (const float4*)Wih_b;
        #pragma unroll
        for (int jj = 0; jj < 4; ++jj) {
            int ch = cb + 64 * jj;
            float4 a0 = wb[ch * 2],               a1 = wb[ch * 2 + 1];
            float4 b0 = wb[(HDIM + ch) * 2],      b1 = wb[(HDIM + ch) * 2 + 1];
            float4 c0v = wb[(2 * HDIM + ch) * 2], c1 = wb[(2 * HDIM + ch) * 2 + 1];
            float ir = bih_b[ch]
                + xv0.x * a0.x + xv0.y * a0.y + xv0.z * a0.z + xv0.w * a0.w
                + xv1.x * a1.x + xv1.y * a1.y + xv1.z * a1.z + xv1.w * a1.w;
            float iz = bih_b[HDIM + ch]
                + xv0.x * b0.x + xv0.y * b0.y + xv0.z * b0.z + xv0.w * b0.w
                + xv1.x * b1.x + xv1.y * b1.y + xv1.z * b1.z + xv1.w * b1.w;
            float inn = bih_b[2 * HDIM + ch]
                + xv0.x * c0v.x + xv0.y * c0v.y + xv0.z * c0v.z + xv0.w * c0v.w
                + xv1.x * c1.x + xv1.y * c1.y + xv1.z * c1.z + xv1.w * c1.w;
            float r = sig_(ir + bhh_b[ch]);
            float z = sig_(iz + bhh_b[HDIM + ch]);
            float n = tanh_(fmaf(r, bhh_b[2 * HDIM + ch], inn));
            float hbw = (1.0f - z) * n;
            int c2 = HDIM + ch;
            lastb[trow][c2 ^ ((trow & 7) << 3)] = (__bf16)hbw;
        }
    }
    __syncthreads();

    // ---- projection: y = gelu(last @ Wp^T + bp); wave w -> cols [16w,16w+16), 16 rows ----
    {
        int col = 16 * w + l15;
        float b = bp[col];
        f32x4 pacc;
        pacc[0] = b; pacc[1] = b; pacc[2] = b; pacc[3] = b;
        #pragma unroll
        for (int kt = 0; kt < 16; ++kt) {
            int c = (kt * 32 + lq * 8) ^ wswz;
            b8 a = *(const b8*)&lastb[l15][c];
            pacc = MFMA(a, wsWP[(w * 16 + kt) * 64 + lane], pacc);
        }
        #pragma unroll
        for (int j = 0; j < 4; ++j) {
            int row = lq * 4 + j;
            float v = pacc[j];
            ybuf[row][col] = 0.5f * v * (1.0f + erff(v * 0.70710678118f));
        }
    }
    __syncthreads();

    // ---- LayerNorm: 16 waves, one row each ----
    {
        int row = w;
        float v[4];
        float s = 0.0f, sq = 0.0f;
        #pragma unroll
        for (int m = 0; m < 4; ++m) {
            v[m] = ybuf[row][lane + 64 * m];
            s += v[m];
            sq += v[m] * v[m];
        }
        #pragma unroll
        for (int off = 32; off >= 1; off >>= 1) {
            s  += __shfl_xor(s, off, 64);
            sq += __shfl_xor(sq, off, 64);
        }
        float mu = s * (1.0f / 256.0f);
        float var = sq * (1.0f / 256.0f) - mu * mu;
        float rs = rsqrtf(var + 1e-5f);
        float* orow = out + (blockRow + row) * HDIM;
        #pragma unroll
        for (int m = 0; m < 4; ++m) {
            int cc = lane + 64 * m;
            orow[cc] = (v[m] - mu) * rs * gamma[cc] + beta[cc];
        }
    }
}

extern "C" void kernel_launch(void* const* d_in, const int* in_sizes, int n_in,
                              void* d_out, int out_size, void* d_ws, size_t ws_size,
                              hipStream_t stream)
{
    const float* x     = (const float*)d_in[0];
    const float* Wih_f = (const float*)d_in[1];
    const float* Whh_f = (const float*)d_in[2];
    const float* bih_f = (const float*)d_in[3];
    const float* bhh_f = (const float*)d_in[4];
    const float* Wih_b = (const float*)d_in[5];
    // d_in[6] = Whh_b unused: h0=0 so gh_b = bhh_b exactly
    const float* bih_b = (const float*)d_in[7];
    const float* bhh_b = (const float*)d_in[8];
    const float* Wp    = (const float*)d_in[9];
    const float* bp    = (const float*)d_in[10];
    const float* gamma = (const float*)d_in[11];
    const float* beta  = (const float*)d_in[12];
    float* out = (float*)d_out;
    unsigned char* ws = (unsigned char*)d_ws;

    // allow 144KB dynamic LDS (host-side attribute, graph-capture safe)
    hipFuncSetAttribute((const void*)gru_main_kernel,
                        hipFuncAttributeMaxDynamicSharedMemorySize, SMEM_BYTES);

    const int packItems = 16384 + 8192 + 3072 + 16384 + 262144;   // 306176
    hipLaunchKernelGGL(pack_kernel, dim3((packItems + 255) / 256), dim3(256), 0, stream,
                       x, Wih_f, Whh_f, bih_f, bhh_f, Wp, ws);
    hipLaunchKernelGGL(gru_main_kernel, dim3(BDIM / 16), dim3(1024), SMEM_BYTES, stream,
                       x, bhh_f, Wih_b, bih_b, bhh_b, bp, gamma, beta, ws, out);
}